// Round 1
// baseline (358.840 us; speedup 1.0000x reference)
//
#include <hip/hip_runtime.h>

// Problem constants (z: [16,256,64,64] f32, embedding: [1024,256] f32)
#define NN 65536   // B*H*W rows
#define KK 1024
// flag if fixed-point top-2 gap < 2098 (= 4e-3 * 2^19): ~10 sigma of 1-pass bf16 noise
#define TFLAG_FIX 2098u

typedef __bf16 bf16x8 __attribute__((ext_vector_type(8)));
typedef float f32x16 __attribute__((ext_vector_type(16)));

__device__ __forceinline__ unsigned short f2bf(float x){
  unsigned u = __float_as_uint(x);
  u += 0x7FFFu + ((u >> 16) & 1u);
  return (unsigned short)(u >> 16);
}
__device__ __forceinline__ float bf2f(unsigned short h){
  return __uint_as_float(((unsigned)h) << 16);
}
__device__ __forceinline__ void dma16(const uint4* g, uint4* l){
  __builtin_amdgcn_global_load_lds(
      (const __attribute__((address_space(1))) void*)g,
      (__attribute__((address_space(3))) void*)l, 16, 0, 0);
}
__device__ __forceinline__ unsigned long long shfl_xor_u64(unsigned long long v, int m){
  unsigned lo = (unsigned)__shfl_xor((int)(unsigned)v, m, 64);
  unsigned hi = (unsigned)__shfl_xor((int)(unsigned)(v >> 32), m, 64);
  return ((unsigned long long)hi << 32) | lo;
}
union U4S8 { uint4 v; unsigned short u[8]; };

// Fragment-major layout for bf16 matrices [rows][256 c]:
// uint4 (8 c-elems) for (row n, chunk q=c>>3) at index (n>>5)*1024 + q*32 + (n&31).

// ---------------- K0: normalize codebook, write wn(f32), wnh frag-major, wnn, wnn4
__global__ __launch_bounds__(64) void kern_prep(const float* __restrict__ emb,
    float* __restrict__ wn, uint4* __restrict__ wnh4,
    float* __restrict__ wnn, float* __restrict__ wnn4)
{
  const int k = blockIdx.x, t = threadIdx.x;
  float4 v = ((const float4*)emb)[k*64 + t];
  float ss = fmaf(v.x, v.x, fmaf(v.y, v.y, fmaf(v.z, v.z, v.w * v.w)));
  #pragma unroll
  for (int m = 32; m > 0; m >>= 1) ss += __shfl_xor(ss, m, 64);
  float d = fmaxf(sqrtf(ss), 1e-12f);
  float w0 = v.x / d, w1 = v.y / d, w2 = v.z / d, w3 = v.w / d;
  ((float4*)wn)[k*64 + t] = make_float4(w0, w1, w2, w3);
  unsigned short* base = (unsigned short*)wnh4;
  size_t o = ((size_t)(k >> 5) * 1024 + (size_t)(t >> 1) * 32 + (k & 31)) * 8 + (t & 1) * 4;
  base[o+0] = f2bf(w0); base[o+1] = f2bf(w1); base[o+2] = f2bf(w2); base[o+3] = f2bf(w3);
  float s2 = fmaf(w0, w0, fmaf(w1, w1, fmaf(w2, w2, w3 * w3)));
  #pragma unroll
  for (int m = 32; m > 0; m >>= 1) s2 += __shfl_xor(s2, m, 64);
  if (t == 0){ wnn[k] = s2; wnn4[k] = 4.0f - s2; }
}

// ---------------- K1: L2-normalize z along W, transpose to [N,C], split bf16 hi/lo,
// store BOTH in fragment-major layout. grid: (b*64+h)*4 + c-tile; block 256.
__global__ __launch_bounds__(256) void kern_znorm(const float* __restrict__ z,
    uint4* __restrict__ zfh4, uint4* __restrict__ zfl4)
{
  __shared__ float tile[64][65];  // [c_local][w]
  __shared__ float sinv[64];
  const int t = threadIdx.x;
  const int ct = blockIdx.x & 3;
  const int bh = blockIdx.x >> 2;     // b*64 + h
  const int c0 = ct * 64, q0 = ct * 8;
  const int cl = t >> 2, q = t & 3;
  const float4* zr = (const float4*)(z + ((size_t)(bh >> 6) * 256 + c0 + cl) * 4096
                                       + (size_t)(bh & 63) * 64);
  #pragma unroll
  for (int i = 0; i < 4; i++){
    float4 v = zr[q + 4*i];
    int w = (q + 4*i) * 4;
    tile[cl][w] = v.x; tile[cl][w+1] = v.y; tile[cl][w+2] = v.z; tile[cl][w+3] = v.w;
  }
  __syncthreads();
  if (t < 64){
    float ss = 0.f;
    #pragma unroll
    for (int w = 0; w < 64; w++){ float x = tile[t][w]; ss = fmaf(x, x, ss); }
    sinv[t] = 1.0f / fmaxf(sqrtf(ss), 1e-12f);
  }
  __syncthreads();
  #pragma unroll
  for (int j = 0; j < 2; j++){
    int p = t + 256 * j;
    int tI = p >> 8, rem = p & 255;
    int qq = rem >> 5, colI = rem & 31;
    int w = tI * 32 + colI;
    U4S8 hh, ll;
    #pragma unroll
    for (int e = 0; e < 8; e++){
      int c = qq * 8 + e;
      float v = tile[c][w] * sinv[c];
      hh.u[e] = f2bf(v);
      ll.u[e] = f2bf(v - bf2f(hh.u[e]));
    }
    size_t o = (size_t)(bh * 2 + tI) * 1024 + (size_t)(q0 + qq) * 32 + colI;
    zfh4[o] = hh.v;
    zfl4[o] = ll.v;
  }
}

// ---------------- K2: 1-pass bf16 MFMA GEMM, 64 rows x 32 codes per wave,
// code-split-2, DMA-staged double-buffered B, fixed-point packed-key top-2 per row.
__global__ __launch_bounds__(256, 2) void kern_gemm(
    const uint4* __restrict__ zA, const uint4* __restrict__ wB,
    const float* __restrict__ wnn4, uint2* __restrict__ pairs)
{
  __shared__ uint4 sB[2][1024];
  const int t = threadIdx.x;
  const int wv = t >> 6;
  const int lane = t & 63;
  const int col = lane & 31;
  const int half = lane >> 5;
  const int hb = blockIdx.x & 1;
  const int cb = hb * 512;
  const int rowBase = (blockIdx.x >> 1) * 256 + wv * 64;
  const int T0 = rowBase >> 5;

  bf16x8 a0[16], a1[16];
  {
    const uint4* r0 = zA + (size_t)T0 * 1024;
    const uint4* r1 = zA + (size_t)(T0 + 1) * 1024;
    const uint4* g0 = wB + (size_t)(cb >> 5) * 1024;
    dma16(g0 + (wv*4+0)*64 + lane, &sB[0][(wv*4+0)*64 + lane]);
    dma16(g0 + (wv*4+1)*64 + lane, &sB[0][(wv*4+1)*64 + lane]);
    dma16(g0 + (wv*4+2)*64 + lane, &sB[0][(wv*4+2)*64 + lane]);
    dma16(g0 + (wv*4+3)*64 + lane, &sB[0][(wv*4+3)*64 + lane]);
    #pragma unroll
    for (int s = 0; s < 16; s++){
      a0[s] = __builtin_bit_cast(bf16x8, r0[(2*s + half)*32 + col]);
      a1[s] = __builtin_bit_cast(bf16x8, r1[(2*s + half)*32 + col]);
    }
  }
  unsigned b1k[2][16], b2k[2][16];
  #pragma unroll
  for (int r = 0; r < 16; r++){
    b1k[0][r] = 0u; b1k[1][r] = 0u; b2k[0][r] = 0u; b2k[1][r] = 0u;
  }
  const int kinvBase = 1023 - cb - col;
  __syncthreads();

  for (int kt = 0; kt < 16; kt++){
    if (kt < 15){
      const uint4* gn = wB + (size_t)((cb >> 5) + kt + 1) * 1024;
      uint4* ld = &sB[(kt + 1) & 1][0];
      dma16(gn + (wv*4+0)*64 + lane, ld + (wv*4+0)*64 + lane);
      dma16(gn + (wv*4+1)*64 + lane, ld + (wv*4+1)*64 + lane);
      dma16(gn + (wv*4+2)*64 + lane, ld + (wv*4+2)*64 + lane);
      dma16(gn + (wv*4+3)*64 + lane, ld + (wv*4+3)*64 + lane);
    }
    const float c4k = wnn4[cb + kt*32 + col];
    const uint4* bp = &sB[kt & 1][half * 32 + col];
    f32x16 acc0, acc1;
    #pragma unroll
    for (int i = 0; i < 16; i++){ acc0[i] = 0.0f; acc1[i] = 0.0f; }
    #pragma unroll
    for (int s = 0; s < 16; s++){
      bf16x8 bs = __builtin_bit_cast(bf16x8, bp[s * 64]);
      acc0 = __builtin_amdgcn_mfma_f32_32x32x16_bf16(a0[s], bs, acc0, 0, 0, 0);
      acc1 = __builtin_amdgcn_mfma_f32_32x32x16_bf16(a1[s], bs, acc1, 0, 0, 0);
    }
    const unsigned kinv = (unsigned)(kinvBase - kt * 32);
    #pragma unroll
    for (int r = 0; r < 16; r++){
      // s'' = 4 - ||w||^2 + 2*dot in [1,5]; fixed-point *2^19 (trunc, monotone)
      float s0 = fmaf(2.0f, acc0[r], c4k);
      unsigned u0 = ((unsigned)(s0 * 524288.0f) << 10) | kinv;
      b2k[0][r] = max(b2k[0][r], min(b1k[0][r], u0));
      b1k[0][r] = max(b1k[0][r], u0);
      float s1 = fmaf(2.0f, acc1[r], c4k);
      unsigned u1 = ((unsigned)(s1 * 524288.0f) << 10) | kinv;
      b2k[1][r] = max(b2k[1][r], min(b1k[1][r], u1));
      b1k[1][r] = max(b1k[1][r], u1);
    }
    __syncthreads();
  }
  #pragma unroll
  for (int m = 1; m < 32; m <<= 1){
    #pragma unroll
    for (int ti = 0; ti < 2; ti++){
      #pragma unroll
      for (int r = 0; r < 16; r++){
        unsigned o1 = (unsigned)__shfl_xor((int)b1k[ti][r], m, 64);
        unsigned o2 = (unsigned)__shfl_xor((int)b2k[ti][r], m, 64);
        b2k[ti][r] = max(max(b2k[ti][r], o2), min(b1k[ti][r], o1));
        b1k[ti][r] = max(b1k[ti][r], o1);
      }
    }
  }
  if (col == 0){
    #pragma unroll
    for (int ti = 0; ti < 2; ti++){
      #pragma unroll
      for (int r = 0; r < 16; r++){
        int rowD = (r & 3) + 8 * (r >> 2) + 4 * half;  // verified C/D map [m74/m101]
        int n = rowBase + ti * 32 + rowD;
        pairs[(size_t)n * 2 + hb] = make_uint2(b1k[ti][r], b2k[ti][r]);
      }
    }
  }
}

// ---------------- K2m: merge two code-half top-2s, emit idx + flags (integer gap)
__global__ __launch_bounds__(256) void kern_merge(
    const uint2* __restrict__ pairs, int* __restrict__ idx_i, float* __restrict__ idx_f,
    int* __restrict__ flag_list, unsigned int* __restrict__ flag_count)
{
  const int n = blockIdx.x * 256 + threadIdx.x;
  uint2 p0 = pairs[(size_t)n * 2];
  uint2 p1 = pairs[(size_t)n * 2 + 1];
  unsigned B1 = max(p0.x, p1.x);
  unsigned B2 = max(max(p0.y, p1.y), min(p0.x, p1.x));
  int idx = 1023 - (int)(B1 & 1023u);
  idx_i[n] = idx;
  idx_f[n] = (float)idx;
  bool f = ((B1 >> 10) - (B2 >> 10)) < TFLAG_FIX;
  unsigned long long m = __ballot(f);
  if (m){
    int lane = threadIdx.x & 63;
    int leader = __ffsll((unsigned long long)m) - 1;
    unsigned base = 0;
    if (lane == leader) base = atomicAdd(flag_count, (unsigned)__popcll(m));
    base = (unsigned)__shfl((int)base, leader, 64);
    if (f){
      int off = __popcll(m & ((1ull << lane) - 1ull));
      flag_list[base + off] = n;
    }
  }
}

// ---------------- K2b: exact-fp32 rescore of flagged rows. Per-(row,k) chain is
// BIT-IDENTICAL to the R1/R3-validated rescue: serial fp32 fmaf over c=0..255
// (zf = hi+lo), s = fmaf(-2, dot, wnn[k]), argmin with lowest-index tie-break
// (realized exactly via 64-bit (orderable-float, k) key min-reduce).
// This round: 8 rows/batch (was 16) + grid 1024 (was 512) — doubles active
// blocks (~cnt/8 of them), halves the per-thread serial fmaf chain (16384->8192),
// and shrinks acc to 32 VGPRs. The per-(row,k) fp32 chain and key tie-break are
// unchanged. Previous counters: dur 78us, VALUBusy 24%, Occupancy 8% -> pure
// occupancy/latency limit; VALU roofline for cnt~6-7k rows is ~20us.
__global__ __launch_bounds__(256) void kern_rescue(
    const uint4* __restrict__ zfh4, const uint4* __restrict__ zfl4,
    const float* __restrict__ wn, const float* __restrict__ wnn,
    const int* __restrict__ flag_list, const unsigned int* __restrict__ flag_count,
    int* __restrict__ idx_i, float* __restrict__ idx_f)
{
  __shared__ float sz[8][256];
  __shared__ unsigned long long sred[4][8];
  __shared__ int srow[8];
  const int t = threadIdx.x;
  const int lane = t & 63, wvi = t >> 6;
  const int cnt = (int)*flag_count;
  if (blockIdx.x * 8 >= cnt) return;    // uniform early-out for idle blocks
  const int k0 = t * 4;
  const float wq0 = wnn[k0+0], wq1 = wnn[k0+1], wq2 = wnn[k0+2], wq3 = wnn[k0+3];

  for (int base = blockIdx.x * 8; base < cnt; base += gridDim.x * 8){
    const int nr = min(8, cnt - base);
    __syncthreads();
    if (t < 8) srow[t] = flag_list[base + min(t, nr - 1)];  // pad: duplicate last row
    __syncthreads();
    {
      int r = t >> 5, q = t & 31;
      int n = srow[r];
      size_t o = (size_t)(n >> 5) * 1024 + (size_t)q * 32 + (n & 31);
      U4S8 h, l; h.v = zfh4[o]; l.v = zfl4[o];
      #pragma unroll
      for (int e = 0; e < 8; e++) sz[r][q*8+e] = bf2f(h.u[e]) + bf2f(l.u[e]);
    }
    __syncthreads();

    float acc[4][8];
    #pragma unroll
    for (int j = 0; j < 4; j++)
      #pragma unroll
      for (int r = 0; r < 8; r++) acc[j][r] = 0.0f;
    const float4* w0 = (const float4*)(wn + (size_t)(k0+0)*256);
    const float4* w1 = (const float4*)(wn + (size_t)(k0+1)*256);
    const float4* w2 = (const float4*)(wn + (size_t)(k0+2)*256);
    const float4* w3 = (const float4*)(wn + (size_t)(k0+3)*256);
    for (int c4 = 0; c4 < 64; c4++){
      float4 wa = w0[c4], wb = w1[c4], wc = w2[c4], wd = w3[c4];
      #pragma unroll
      for (int r = 0; r < 8; r++){
        float4 s = ((const float4*)sz[r])[c4];   // broadcast LDS read
        acc[0][r] = fmaf(s.x, wa.x, acc[0][r]);
        acc[0][r] = fmaf(s.y, wa.y, acc[0][r]);
        acc[0][r] = fmaf(s.z, wa.z, acc[0][r]);
        acc[0][r] = fmaf(s.w, wa.w, acc[0][r]);
        acc[1][r] = fmaf(s.x, wb.x, acc[1][r]);
        acc[1][r] = fmaf(s.y, wb.y, acc[1][r]);
        acc[1][r] = fmaf(s.z, wb.z, acc[1][r]);
        acc[1][r] = fmaf(s.w, wb.w, acc[1][r]);
        acc[2][r] = fmaf(s.x, wc.x, acc[2][r]);
        acc[2][r] = fmaf(s.y, wc.y, acc[2][r]);
        acc[2][r] = fmaf(s.z, wc.z, acc[2][r]);
        acc[2][r] = fmaf(s.w, wc.w, acc[2][r]);
        acc[3][r] = fmaf(s.x, wd.x, acc[3][r]);
        acc[3][r] = fmaf(s.y, wd.y, acc[3][r]);
        acc[3][r] = fmaf(s.z, wd.z, acc[3][r]);
        acc[3][r] = fmaf(s.w, wd.w, acc[3][r]);
      }
    }
    #pragma unroll
    for (int r = 0; r < 8; r++){
      float s0 = fmaf(-2.0f, acc[0][r], wq0);
      float s1 = fmaf(-2.0f, acc[1][r], wq1);
      float s2 = fmaf(-2.0f, acc[2][r], wq2);
      float s3 = fmaf(-2.0f, acc[3][r], wq3);
      float bv = s0; int bi = k0;
      if (s1 < bv){ bv = s1; bi = k0 + 1; }
      if (s2 < bv){ bv = s2; bi = k0 + 2; }
      if (s3 < bv){ bv = s3; bi = k0 + 3; }
      unsigned u = __float_as_uint(bv);
      u = (u & 0x80000000u) ? ~u : (u | 0x80000000u);   // orderable float
      unsigned long long key = ((unsigned long long)u << 10) | (unsigned)bi;
      #pragma unroll
      for (int m = 1; m < 64; m <<= 1){
        unsigned long long o = shfl_xor_u64(key, m);
        if (o < key) key = o;
      }
      if (lane == 0) sred[wvi][r] = key;
    }
    __syncthreads();
    if (t < nr){
      unsigned long long ka = sred[0][t] < sred[1][t] ? sred[0][t] : sred[1][t];
      unsigned long long kb = sred[2][t] < sred[3][t] ? sred[2][t] : sred[3][t];
      unsigned long long kf = ka < kb ? ka : kb;
      int fi = (int)(kf & 1023ull);
      idx_i[srow[t]] = fi;
      idx_f[srow[t]] = (float)fi;
    }
  }
}

// ---------------- K3: gather z_q = embedding[idx] back to [B,C,H,W] + loss sum
__global__ __launch_bounds__(256) void kern_gather(
    const float* __restrict__ z, const float* __restrict__ emb,
    const int* __restrict__ idx_i, float* __restrict__ out,
    float* __restrict__ loss_acc)
{
  __shared__ float tile[64][65];
  __shared__ float zq[64][65];
  __shared__ float sinv[64];
  __shared__ int sidx[64];
  __shared__ float swsum[4];
  const int t = threadIdx.x;
  const int ct = blockIdx.x & 3;
  const int bh = blockIdx.x >> 2;
  const int c0 = ct * 64;
  const int cl = t >> 2, q = t & 3;
  const float4* zr = (const float4*)(z + ((size_t)(bh >> 6) * 256 + c0 + cl) * 4096
                                       + (size_t)(bh & 63) * 64);
  #pragma unroll
  for (int i = 0; i < 4; i++){
    float4 v = zr[q + 4*i];
    int w = (q + 4*i) * 4;
    tile[cl][w] = v.x; tile[cl][w+1] = v.y; tile[cl][w+2] = v.z; tile[cl][w+3] = v.w;
  }
  if (t < 64) sidx[t] = idx_i[bh*64 + t];
  __syncthreads();
  if (t < 64){
    float ss = 0.f;
    #pragma unroll
    for (int w = 0; w < 64; w++){ float x = tile[t][w]; ss = fmaf(x, x, ss); }
    sinv[t] = 1.0f / fmaxf(sqrtf(ss), 1e-12f);
  }
  __syncthreads();
  {
    const int wvv = t >> 6, l = t & 63;
    #pragma unroll
    for (int i = 0; i < 16; i++){
      int w = wvv * 16 + i;
      zq[l][w] = emb[(size_t)sidx[w] * 256 + c0 + l];
    }
  }
  __syncthreads();
  float lsum = 0.f;
  const int rr = t >> 4, w4 = (t & 15) * 4;
  #pragma unroll
  for (int rd = 0; rd < 4; rd++){
    int r = rr + 16 * rd;
    float inv = sinv[r];
    float q0 = zq[r][w4+0], q1 = zq[r][w4+1], q2 = zq[r][w4+2], q3 = zq[r][w4+3];
    float d0 = q0 - tile[r][w4+0] * inv;
    float d1 = q1 - tile[r][w4+1] * inv;
    float d2 = q2 - tile[r][w4+2] * inv;
    float d3 = q3 - tile[r][w4+3] * inv;
    lsum = fmaf(d0, d0, lsum); lsum = fmaf(d1, d1, lsum);
    lsum = fmaf(d2, d2, lsum); lsum = fmaf(d3, d3, lsum);
    *(float4*)(out + ((size_t)(bh >> 6) * 256 + c0 + r) * 4096
                   + (size_t)(bh & 63) * 64 + w4) = make_float4(q0, q1, q2, q3);
  }
  #pragma unroll
  for (int m = 32; m > 0; m >>= 1) lsum += __shfl_down(lsum, m, 64);
  if ((t & 63) == 0) swsum[t >> 6] = lsum;
  __syncthreads();
  if (t == 0) atomicAdd(loss_acc, swsum[0] + swsum[1] + swsum[2] + swsum[3]);
}

// ---------------- K4: finalize loss = (1 + BETA) * mean
__global__ void kern_final(const float* __restrict__ loss_acc, float* __restrict__ out_loss){
  if (threadIdx.x == 0 && blockIdx.x == 0)
    out_loss[0] = 1.25f * loss_acc[0] * (1.0f / 16777216.0f);
}

extern "C" void kernel_launch(void* const* d_in, const int* in_sizes, int n_in,
                              void* d_out, int out_size, void* d_ws, size_t ws_size,
                              hipStream_t stream)
{
  const float* z   = (const float*)d_in[0];
  const float* emb = (const float*)d_in[1];
  char* ws = (char*)d_ws;
  unsigned int* flag_count = (unsigned int*)(ws + 0);
  float* loss_acc          = (float*)(ws + 8);
  float* wnn               = (float*)(ws + 1024);
  float* wnn4              = (float*)(ws + 8192);
  float* wn                = (float*)(ws + 16384);
  uint4* wnh4              = (uint4*)(ws + 1064960);
  int* idx_i               = (int*)(ws + 1589248);
  int* flag_list           = (int*)(ws + 1851392);
  uint2* pairs             = (uint2*)(ws + 2113536);
  uint4* zfh4              = (uint4*)(ws + 3162112);
  uint4* zfl4              = (uint4*)(ws + 36716544);
  float* out_zq   = (float*)d_out;
  float* out_idx  = (float*)d_out + 16777216;
  float* out_loss = (float*)d_out + 16842752;

  hipMemsetAsync(ws, 0, 16, stream);  // flag_count + loss accumulator
  kern_prep<<<KK, 64, 0, stream>>>(emb, wn, wnh4, wnn, wnn4);
  kern_znorm<<<4096, 256, 0, stream>>>(z, zfh4, zfl4);
  kern_gemm<<<512, 256, 0, stream>>>(zfh4, wnh4, wnn4, pairs);
  kern_merge<<<256, 256, 0, stream>>>(pairs, idx_i, out_idx, flag_list, flag_count);
  kern_rescue<<<1024, 256, 0, stream>>>(zfh4, zfl4, wn, wnn, flag_list, flag_count,
                                        idx_i, out_idx);
  kern_gather<<<4096, 256, 0, stream>>>(z, emb, idx_i, out_zq, loss_acc);
  kern_final<<<1, 64, 0, stream>>>(loss_acc, out_loss);
}

// Round 2
// 287.695 us; speedup vs baseline: 1.2473x; 1.2473x over previous
//
#include <hip/hip_runtime.h>

// Problem constants (z: [16,256,64,64] f32, embedding: [1024,256] f32)
#define NN 65536   // B*H*W rows
#define KK 1024
// flag if fixed-point top-2 gap < 2098 (= 4e-3 * 2^19): ~10 sigma of 1-pass bf16 noise
#define TFLAG_FIX 2098u

typedef __bf16 bf16x8 __attribute__((ext_vector_type(8)));
typedef float f32x16 __attribute__((ext_vector_type(16)));

__device__ __forceinline__ unsigned short f2bf(float x){
  unsigned u = __float_as_uint(x);
  u += 0x7FFFu + ((u >> 16) & 1u);
  return (unsigned short)(u >> 16);
}
__device__ __forceinline__ float bf2f(unsigned short h){
  return __uint_as_float(((unsigned)h) << 16);
}
__device__ __forceinline__ void dma16(const uint4* g, uint4* l){
  __builtin_amdgcn_global_load_lds(
      (const __attribute__((address_space(1))) void*)g,
      (__attribute__((address_space(3))) void*)l, 16, 0, 0);
}
__device__ __forceinline__ unsigned long long shfl_xor_u64(unsigned long long v, int m){
  unsigned lo = (unsigned)__shfl_xor((int)(unsigned)v, m, 64);
  unsigned hi = (unsigned)__shfl_xor((int)(unsigned)(v >> 32), m, 64);
  return ((unsigned long long)hi << 32) | lo;
}
union U4S8 { uint4 v; unsigned short u[8]; };

// Fragment-major layout for bf16 matrices [rows][256 c]:
// uint4 (8 c-elems) for (row n, chunk q=c>>3) at index (n>>5)*1024 + q*32 + (n&31).

// ---------------- K0: normalize codebook. wnT is stored TRANSPOSED [c][k] (f32)
// so kern_rescue's per-channel codebook read is wave-coalesced (lane t reads
// wnT[c][4t..4t+3] -> contiguous 1KB per wave instead of 64 scattered lines).
__global__ __launch_bounds__(64) void kern_prep(const float* __restrict__ emb,
    float* __restrict__ wnT, uint4* __restrict__ wnh4,
    float* __restrict__ wnn, float* __restrict__ wnn4)
{
  const int k = blockIdx.x, t = threadIdx.x;
  float4 v = ((const float4*)emb)[k*64 + t];
  float ss = fmaf(v.x, v.x, fmaf(v.y, v.y, fmaf(v.z, v.z, v.w * v.w)));
  #pragma unroll
  for (int m = 32; m > 0; m >>= 1) ss += __shfl_xor(ss, m, 64);
  float d = fmaxf(sqrtf(ss), 1e-12f);
  float w0 = v.x / d, w1 = v.y / d, w2 = v.z / d, w3 = v.w / d;
  // transposed store: wnT[c][k], c = 4t..4t+3 (one-time scattered 1MB write)
  wnT[(size_t)(4*t+0)*1024 + k] = w0;
  wnT[(size_t)(4*t+1)*1024 + k] = w1;
  wnT[(size_t)(4*t+2)*1024 + k] = w2;
  wnT[(size_t)(4*t+3)*1024 + k] = w3;
  unsigned short* base = (unsigned short*)wnh4;
  size_t o = ((size_t)(k >> 5) * 1024 + (size_t)(t >> 1) * 32 + (k & 31)) * 8 + (t & 1) * 4;
  base[o+0] = f2bf(w0); base[o+1] = f2bf(w1); base[o+2] = f2bf(w2); base[o+3] = f2bf(w3);
  float s2 = fmaf(w0, w0, fmaf(w1, w1, fmaf(w2, w2, w3 * w3)));
  #pragma unroll
  for (int m = 32; m > 0; m >>= 1) s2 += __shfl_xor(s2, m, 64);
  if (t == 0){ wnn[k] = s2; wnn4[k] = 4.0f - s2; }
}

// ---------------- K1: L2-normalize z along W, transpose to [N,C], split bf16 hi/lo,
// store BOTH in fragment-major layout. grid: (b*64+h)*4 + c-tile; block 256.
__global__ __launch_bounds__(256) void kern_znorm(const float* __restrict__ z,
    uint4* __restrict__ zfh4, uint4* __restrict__ zfl4)
{
  __shared__ float tile[64][65];  // [c_local][w]
  __shared__ float sinv[64];
  const int t = threadIdx.x;
  const int ct = blockIdx.x & 3;
  const int bh = blockIdx.x >> 2;     // b*64 + h
  const int c0 = ct * 64, q0 = ct * 8;
  const int cl = t >> 2, q = t & 3;
  const float4* zr = (const float4*)(z + ((size_t)(bh >> 6) * 256 + c0 + cl) * 4096
                                       + (size_t)(bh & 63) * 64);
  #pragma unroll
  for (int i = 0; i < 4; i++){
    float4 v = zr[q + 4*i];
    int w = (q + 4*i) * 4;
    tile[cl][w] = v.x; tile[cl][w+1] = v.y; tile[cl][w+2] = v.z; tile[cl][w+3] = v.w;
  }
  __syncthreads();
  if (t < 64){
    float ss = 0.f;
    #pragma unroll
    for (int w = 0; w < 64; w++){ float x = tile[t][w]; ss = fmaf(x, x, ss); }
    sinv[t] = 1.0f / fmaxf(sqrtf(ss), 1e-12f);
  }
  __syncthreads();
  #pragma unroll
  for (int j = 0; j < 2; j++){
    int p = t + 256 * j;
    int tI = p >> 8, rem = p & 255;
    int qq = rem >> 5, colI = rem & 31;
    int w = tI * 32 + colI;
    U4S8 hh, ll;
    #pragma unroll
    for (int e = 0; e < 8; e++){
      int c = qq * 8 + e;
      float v = tile[c][w] * sinv[c];
      hh.u[e] = f2bf(v);
      ll.u[e] = f2bf(v - bf2f(hh.u[e]));
    }
    size_t o = (size_t)(bh * 2 + tI) * 1024 + (size_t)(q0 + qq) * 32 + colI;
    zfh4[o] = hh.v;
    zfl4[o] = ll.v;
  }
}

// ---------------- K2: 1-pass bf16 MFMA GEMM, 64 rows x 32 codes per wave,
// code-split-2, DMA-staged double-buffered B, fixed-point packed-key top-2 per row.
__global__ __launch_bounds__(256, 2) void kern_gemm(
    const uint4* __restrict__ zA, const uint4* __restrict__ wB,
    const float* __restrict__ wnn4, uint2* __restrict__ pairs)
{
  __shared__ uint4 sB[2][1024];
  const int t = threadIdx.x;
  const int wv = t >> 6;
  const int lane = t & 63;
  const int col = lane & 31;
  const int half = lane >> 5;
  const int hb = blockIdx.x & 1;
  const int cb = hb * 512;
  const int rowBase = (blockIdx.x >> 1) * 256 + wv * 64;
  const int T0 = rowBase >> 5;

  bf16x8 a0[16], a1[16];
  {
    const uint4* r0 = zA + (size_t)T0 * 1024;
    const uint4* r1 = zA + (size_t)(T0 + 1) * 1024;
    const uint4* g0 = wB + (size_t)(cb >> 5) * 1024;
    dma16(g0 + (wv*4+0)*64 + lane, &sB[0][(wv*4+0)*64 + lane]);
    dma16(g0 + (wv*4+1)*64 + lane, &sB[0][(wv*4+1)*64 + lane]);
    dma16(g0 + (wv*4+2)*64 + lane, &sB[0][(wv*4+2)*64 + lane]);
    dma16(g0 + (wv*4+3)*64 + lane, &sB[0][(wv*4+3)*64 + lane]);
    #pragma unroll
    for (int s = 0; s < 16; s++){
      a0[s] = __builtin_bit_cast(bf16x8, r0[(2*s + half)*32 + col]);
      a1[s] = __builtin_bit_cast(bf16x8, r1[(2*s + half)*32 + col]);
    }
  }
  unsigned b1k[2][16], b2k[2][16];
  #pragma unroll
  for (int r = 0; r < 16; r++){
    b1k[0][r] = 0u; b1k[1][r] = 0u; b2k[0][r] = 0u; b2k[1][r] = 0u;
  }
  const int kinvBase = 1023 - cb - col;
  __syncthreads();

  for (int kt = 0; kt < 16; kt++){
    if (kt < 15){
      const uint4* gn = wB + (size_t)((cb >> 5) + kt + 1) * 1024;
      uint4* ld = &sB[(kt + 1) & 1][0];
      dma16(gn + (wv*4+0)*64 + lane, ld + (wv*4+0)*64 + lane);
      dma16(gn + (wv*4+1)*64 + lane, ld + (wv*4+1)*64 + lane);
      dma16(gn + (wv*4+2)*64 + lane, ld + (wv*4+2)*64 + lane);
      dma16(gn + (wv*4+3)*64 + lane, ld + (wv*4+3)*64 + lane);
    }
    const float c4k = wnn4[cb + kt*32 + col];
    const uint4* bp = &sB[kt & 1][half * 32 + col];
    f32x16 acc0, acc1;
    #pragma unroll
    for (int i = 0; i < 16; i++){ acc0[i] = 0.0f; acc1[i] = 0.0f; }
    #pragma unroll
    for (int s = 0; s < 16; s++){
      bf16x8 bs = __builtin_bit_cast(bf16x8, bp[s * 64]);
      acc0 = __builtin_amdgcn_mfma_f32_32x32x16_bf16(a0[s], bs, acc0, 0, 0, 0);
      acc1 = __builtin_amdgcn_mfma_f32_32x32x16_bf16(a1[s], bs, acc1, 0, 0, 0);
    }
    const unsigned kinv = (unsigned)(kinvBase - kt * 32);
    #pragma unroll
    for (int r = 0; r < 16; r++){
      // s'' = 4 - ||w||^2 + 2*dot in [1,5]; fixed-point *2^19 (trunc, monotone)
      float s0 = fmaf(2.0f, acc0[r], c4k);
      unsigned u0 = ((unsigned)(s0 * 524288.0f) << 10) | kinv;
      b2k[0][r] = max(b2k[0][r], min(b1k[0][r], u0));
      b1k[0][r] = max(b1k[0][r], u0);
      float s1 = fmaf(2.0f, acc1[r], c4k);
      unsigned u1 = ((unsigned)(s1 * 524288.0f) << 10) | kinv;
      b2k[1][r] = max(b2k[1][r], min(b1k[1][r], u1));
      b1k[1][r] = max(b1k[1][r], u1);
    }
    __syncthreads();
  }
  #pragma unroll
  for (int m = 1; m < 32; m <<= 1){
    #pragma unroll
    for (int ti = 0; ti < 2; ti++){
      #pragma unroll
      for (int r = 0; r < 16; r++){
        unsigned o1 = (unsigned)__shfl_xor((int)b1k[ti][r], m, 64);
        unsigned o2 = (unsigned)__shfl_xor((int)b2k[ti][r], m, 64);
        b2k[ti][r] = max(max(b2k[ti][r], o2), min(b1k[ti][r], o1));
        b1k[ti][r] = max(b1k[ti][r], o1);
      }
    }
  }
  if (col == 0){
    #pragma unroll
    for (int ti = 0; ti < 2; ti++){
      #pragma unroll
      for (int r = 0; r < 16; r++){
        int rowD = (r & 3) + 8 * (r >> 2) + 4 * half;  // verified C/D map [m74/m101]
        int n = rowBase + ti * 32 + rowD;
        pairs[(size_t)n * 2 + hb] = make_uint2(b1k[ti][r], b2k[ti][r]);
      }
    }
  }
}

// ---------------- K2m: merge two code-half top-2s, emit idx + flags (integer gap)
__global__ __launch_bounds__(256) void kern_merge(
    const uint2* __restrict__ pairs, int* __restrict__ idx_i, float* __restrict__ idx_f,
    int* __restrict__ flag_list, unsigned int* __restrict__ flag_count)
{
  const int n = blockIdx.x * 256 + threadIdx.x;
  uint2 p0 = pairs[(size_t)n * 2];
  uint2 p1 = pairs[(size_t)n * 2 + 1];
  unsigned B1 = max(p0.x, p1.x);
  unsigned B2 = max(max(p0.y, p1.y), min(p0.x, p1.x));
  int idx = 1023 - (int)(B1 & 1023u);
  idx_i[n] = idx;
  idx_f[n] = (float)idx;
  bool f = ((B1 >> 10) - (B2 >> 10)) < TFLAG_FIX;
  unsigned long long m = __ballot(f);
  if (m){
    int lane = threadIdx.x & 63;
    int leader = __ffsll((unsigned long long)m) - 1;
    unsigned base = 0;
    if (lane == leader) base = atomicAdd(flag_count, (unsigned)__popcll(m));
    base = (unsigned)__shfl((int)base, leader, 64);
    if (f){
      int off = __popcll(m & ((1ull << lane) - 1ull));
      flag_list[base + off] = n;
    }
  }
}

// ---------------- K2b: exact-fp32 rescore of flagged rows. Per-(row,k) chain is
// BIT-IDENTICAL to the R1/R3-validated rescue: serial fp32 fmaf over c=0..255
// (zf = hi+lo), s = fmaf(-2, dot, wnn[k]), argmin with lowest-index tie-break
// (realized exactly via 64-bit (orderable-float, k) key min-reduce).
// R5 post-mortem: the codebook read was the bottleneck — thread t reading rows
// k0=4t..4t+3 of wn[k][c] makes each wave-load touch 64 distinct cache lines
// (lane stride 4KB). R6: codebook stored TRANSPOSED wnT[c][k]; at channel c,
// lane t reads wnT[c][4t..4t+3] -> one contiguous 1KB span per wave-load (16x
// fewer L2 transactions). fmaf order per (row,k) chain unchanged: component j
// of cv0..cv3 == old wa/wb/wc/wd channel sequence. 16 rows/batch, grid 512
// (R5's 8-row split doubled codebook re-reads and regressed — reverted).
__global__ __launch_bounds__(256) void kern_rescue(
    const uint4* __restrict__ zfh4, const uint4* __restrict__ zfl4,
    const float* __restrict__ wnT, const float* __restrict__ wnn,
    const int* __restrict__ flag_list, const unsigned int* __restrict__ flag_count,
    int* __restrict__ idx_i, float* __restrict__ idx_f)
{
  __shared__ float sz[16][256];
  __shared__ unsigned long long sred[4][16];
  __shared__ int srow[16];
  const int t = threadIdx.x;
  const int lane = t & 63, wvi = t >> 6;
  const int cnt = (int)*flag_count;
  if (blockIdx.x * 16 >= cnt) return;   // uniform early-out for idle blocks
  const int k0 = t * 4;
  const float wq0 = wnn[k0+0], wq1 = wnn[k0+1], wq2 = wnn[k0+2], wq3 = wnn[k0+3];
  const float4* wt = (const float4*)wnT;   // [256][1024] f32 -> float4 idx c*256 + t

  for (int base = blockIdx.x * 16; base < cnt; base += gridDim.x * 16){
    const int nr = min(16, cnt - base);
    __syncthreads();
    if (t < 16) srow[t] = flag_list[base + min(t, nr - 1)];  // pad: duplicate last row
    __syncthreads();
    #pragma unroll
    for (int j = 0; j < 2; j++){
      int p = t + j * 256;
      int r = p >> 5, q = p & 31;
      int n = srow[r];
      size_t o = (size_t)(n >> 5) * 1024 + (size_t)q * 32 + (n & 31);
      U4S8 h, l; h.v = zfh4[o]; l.v = zfl4[o];
      #pragma unroll
      for (int e = 0; e < 8; e++) sz[r][q*8+e] = bf2f(h.u[e]) + bf2f(l.u[e]);
    }
    __syncthreads();

    float acc[4][16];
    #pragma unroll
    for (int j = 0; j < 4; j++)
      #pragma unroll
      for (int r = 0; r < 16; r++) acc[j][r] = 0.0f;
    for (int c4 = 0; c4 < 64; c4++){
      // coalesced: each load = wave-contiguous 1KB of wnT row (channel 4*c4+i)
      float4 cv0 = wt[(size_t)(4*c4+0)*256 + t];
      float4 cv1 = wt[(size_t)(4*c4+1)*256 + t];
      float4 cv2 = wt[(size_t)(4*c4+2)*256 + t];
      float4 cv3 = wt[(size_t)(4*c4+3)*256 + t];
      #pragma unroll
      for (int r = 0; r < 16; r++){
        float4 s = ((const float4*)sz[r])[c4];   // broadcast LDS read
        acc[0][r] = fmaf(s.x, cv0.x, acc[0][r]);
        acc[0][r] = fmaf(s.y, cv1.x, acc[0][r]);
        acc[0][r] = fmaf(s.z, cv2.x, acc[0][r]);
        acc[0][r] = fmaf(s.w, cv3.x, acc[0][r]);
        acc[1][r] = fmaf(s.x, cv0.y, acc[1][r]);
        acc[1][r] = fmaf(s.y, cv1.y, acc[1][r]);
        acc[1][r] = fmaf(s.z, cv2.y, acc[1][r]);
        acc[1][r] = fmaf(s.w, cv3.y, acc[1][r]);
        acc[2][r] = fmaf(s.x, cv0.z, acc[2][r]);
        acc[2][r] = fmaf(s.y, cv1.z, acc[2][r]);
        acc[2][r] = fmaf(s.z, cv2.z, acc[2][r]);
        acc[2][r] = fmaf(s.w, cv3.z, acc[2][r]);
        acc[3][r] = fmaf(s.x, cv0.w, acc[3][r]);
        acc[3][r] = fmaf(s.y, cv1.w, acc[3][r]);
        acc[3][r] = fmaf(s.z, cv2.w, acc[3][r]);
        acc[3][r] = fmaf(s.w, cv3.w, acc[3][r]);
      }
    }
    #pragma unroll
    for (int r = 0; r < 16; r++){
      float s0 = fmaf(-2.0f, acc[0][r], wq0);
      float s1 = fmaf(-2.0f, acc[1][r], wq1);
      float s2 = fmaf(-2.0f, acc[2][r], wq2);
      float s3 = fmaf(-2.0f, acc[3][r], wq3);
      float bv = s0; int bi = k0;
      if (s1 < bv){ bv = s1; bi = k0 + 1; }
      if (s2 < bv){ bv = s2; bi = k0 + 2; }
      if (s3 < bv){ bv = s3; bi = k0 + 3; }
      unsigned u = __float_as_uint(bv);
      u = (u & 0x80000000u) ? ~u : (u | 0x80000000u);   // orderable float
      unsigned long long key = ((unsigned long long)u << 10) | (unsigned)bi;
      #pragma unroll
      for (int m = 1; m < 64; m <<= 1){
        unsigned long long o = shfl_xor_u64(key, m);
        if (o < key) key = o;
      }
      if (lane == 0) sred[wvi][r] = key;
    }
    __syncthreads();
    if (t < nr){
      unsigned long long ka = sred[0][t] < sred[1][t] ? sred[0][t] : sred[1][t];
      unsigned long long kb = sred[2][t] < sred[3][t] ? sred[2][t] : sred[3][t];
      unsigned long long kf = ka < kb ? ka : kb;
      int fi = (int)(kf & 1023ull);
      idx_i[srow[t]] = fi;
      idx_f[srow[t]] = (float)fi;
    }
  }
}

// ---------------- K3: gather z_q = embedding[idx] back to [B,C,H,W] + loss sum
__global__ __launch_bounds__(256) void kern_gather(
    const float* __restrict__ z, const float* __restrict__ emb,
    const int* __restrict__ idx_i, float* __restrict__ out,
    float* __restrict__ loss_acc)
{
  __shared__ float tile[64][65];
  __shared__ float zq[64][65];
  __shared__ float sinv[64];
  __shared__ int sidx[64];
  __shared__ float swsum[4];
  const int t = threadIdx.x;
  const int ct = blockIdx.x & 3;
  const int bh = blockIdx.x >> 2;
  const int c0 = ct * 64;
  const int cl = t >> 2, q = t & 3;
  const float4* zr = (const float4*)(z + ((size_t)(bh >> 6) * 256 + c0 + cl) * 4096
                                       + (size_t)(bh & 63) * 64);
  #pragma unroll
  for (int i = 0; i < 4; i++){
    float4 v = zr[q + 4*i];
    int w = (q + 4*i) * 4;
    tile[cl][w] = v.x; tile[cl][w+1] = v.y; tile[cl][w+2] = v.z; tile[cl][w+3] = v.w;
  }
  if (t < 64) sidx[t] = idx_i[bh*64 + t];
  __syncthreads();
  if (t < 64){
    float ss = 0.f;
    #pragma unroll
    for (int w = 0; w < 64; w++){ float x = tile[t][w]; ss = fmaf(x, x, ss); }
    sinv[t] = 1.0f / fmaxf(sqrtf(ss), 1e-12f);
  }
  __syncthreads();
  {
    const int wvv = t >> 6, l = t & 63;
    #pragma unroll
    for (int i = 0; i < 16; i++){
      int w = wvv * 16 + i;
      zq[l][w] = emb[(size_t)sidx[w] * 256 + c0 + l];
    }
  }
  __syncthreads();
  float lsum = 0.f;
  const int rr = t >> 4, w4 = (t & 15) * 4;
  #pragma unroll
  for (int rd = 0; rd < 4; rd++){
    int r = rr + 16 * rd;
    float inv = sinv[r];
    float q0 = zq[r][w4+0], q1 = zq[r][w4+1], q2 = zq[r][w4+2], q3 = zq[r][w4+3];
    float d0 = q0 - tile[r][w4+0] * inv;
    float d1 = q1 - tile[r][w4+1] * inv;
    float d2 = q2 - tile[r][w4+2] * inv;
    float d3 = q3 - tile[r][w4+3] * inv;
    lsum = fmaf(d0, d0, lsum); lsum = fmaf(d1, d1, lsum);
    lsum = fmaf(d2, d2, lsum); lsum = fmaf(d3, d3, lsum);
    *(float4*)(out + ((size_t)(bh >> 6) * 256 + c0 + r) * 4096
                   + (size_t)(bh & 63) * 64 + w4) = make_float4(q0, q1, q2, q3);
  }
  #pragma unroll
  for (int m = 32; m > 0; m >>= 1) lsum += __shfl_down(lsum, m, 64);
  if ((t & 63) == 0) swsum[t >> 6] = lsum;
  __syncthreads();
  if (t == 0) atomicAdd(loss_acc, swsum[0] + swsum[1] + swsum[2] + swsum[3]);
}

// ---------------- K4: finalize loss = (1 + BETA) * mean
__global__ void kern_final(const float* __restrict__ loss_acc, float* __restrict__ out_loss){
  if (threadIdx.x == 0 && blockIdx.x == 0)
    out_loss[0] = 1.25f * loss_acc[0] * (1.0f / 16777216.0f);
}

extern "C" void kernel_launch(void* const* d_in, const int* in_sizes, int n_in,
                              void* d_out, int out_size, void* d_ws, size_t ws_size,
                              hipStream_t stream)
{
  const float* z   = (const float*)d_in[0];
  const float* emb = (const float*)d_in[1];
  char* ws = (char*)d_ws;
  unsigned int* flag_count = (unsigned int*)(ws + 0);
  float* loss_acc          = (float*)(ws + 8);
  float* wnn               = (float*)(ws + 1024);
  float* wnn4              = (float*)(ws + 8192);
  float* wnT               = (float*)(ws + 16384);   // transposed codebook [256][1024] f32
  uint4* wnh4              = (uint4*)(ws + 1064960);
  int* idx_i               = (int*)(ws + 1589248);
  int* flag_list           = (int*)(ws + 1851392);
  uint2* pairs             = (uint2*)(ws + 2113536);
  uint4* zfh4              = (uint4*)(ws + 3162112);
  uint4* zfl4              = (uint4*)(ws + 36716544);
  float* out_zq   = (float*)d_out;
  float* out_idx  = (float*)d_out + 16777216;
  float* out_loss = (float*)d_out + 16842752;

  hipMemsetAsync(ws, 0, 16, stream);  // flag_count + loss accumulator
  kern_prep<<<KK, 64, 0, stream>>>(emb, wnT, wnh4, wnn, wnn4);
  kern_znorm<<<4096, 256, 0, stream>>>(z, zfh4, zfl4);
  kern_gemm<<<512, 256, 0, stream>>>(zfh4, wnh4, wnn4, pairs);
  kern_merge<<<256, 256, 0, stream>>>(pairs, idx_i, out_idx, flag_list, flag_count);
  kern_rescue<<<512, 256, 0, stream>>>(zfh4, zfl4, wnT, wnn, flag_list, flag_count,
                                       idx_i, out_idx);
  kern_gather<<<4096, 256, 0, stream>>>(z, emb, idx_i, out_zq, loss_acc);
  kern_final<<<1, 64, 0, stream>>>(loss_acc, out_loss);
}